// Round 6
// baseline (387.195 us; speedup 1.0000x reference)
//
#include <hip/hip_runtime.h>
#include <hip/hip_bf16.h>

// GaussianConv: 5-layer KNN conv net on point cloud.
// R6: conv0 = R4's global_load_lds staging + counted-vmcnt pipeline:
//  - 4 LDS buffers, gll issued 3 chunks ahead
//  - raw s_barrier with explicit s_waitcnt vmcnt(2) (never drains the
//    in-flight prefetch; the structural vmcnt(0) stall is gone)
//  - 512 thr / 8 waves, acc[2][4] (32 AGPR), launch_bounds(512,4) -> 4 w/SIMD
// Layers 1-4 unchanged from R5 (f16 activations, composed idx3).

typedef __attribute__((ext_vector_type(8))) _Float16 f16x8;
typedef __attribute__((ext_vector_type(4))) float f32x4;
typedef __attribute__((ext_vector_type(8))) unsigned short u16x8;

#define NPTS 100000
#define N1PTS 12500

__device__ __forceinline__ void gload_lds16(const unsigned short* g, unsigned short* l) {
  __builtin_amdgcn_global_load_lds(
      (const __attribute__((address_space(1))) void*)g,
      (__attribute__((address_space(3))) void*)l, 16, 0, 0);
}

// Swizzled LDS offset for [64 rows][64 k] f16 tiles (layers 1-4 kernel).
__device__ __forceinline__ int swz(int r, int k) {
  return r * 64 + ((((k >> 3) ^ r) & 7) << 3) + (k & 7);
}

__device__ __forceinline__ unsigned short f16bits(float x) {
  return __builtin_bit_cast(unsigned short, (_Float16)x);
}

// layers 1-4 weights: f32 -> f16 row-major
__global__ void prepack_w(const float* __restrict__ W, unsigned short* __restrict__ out,
                          int n) {
  int i = blockIdx.x * 256 + threadIdx.x;
  if (i < n) out[i] = f16bits(W[i]);
}

// Layer-0 weights -> MFMA-fragment-native packed f16:
// group g = (((c*4 + w)*4 + n)*2 + s), lane l, elem e:
//   dest[g*512 + l*8 + e] = W[w*64+n*16+(l&15)][c*64 + s*32 + (l>>4)*8 + e]
__global__ void prepack_w0(const float* __restrict__ W, unsigned short* __restrict__ out) {
  const int tid = blockIdx.x * 256 + threadIdx.x;  // 65536 total
  const int l = tid & 63;
  const int s = (tid >> 6) & 1;
  const int n = (tid >> 7) & 3;
  const int w = (tid >> 9) & 3;
  const int c = tid >> 11;  // 0..31
  const int co = w * 64 + n * 16 + (l & 15);
  const int k = c * 64 + s * 32 + ((l >> 4) << 3);
  const float* src = W + (size_t)co * 2048 + k;
  u16x8 h;
#pragma unroll
  for (int e = 0; e < 8; ++e) h[e] = f16bits(src[e]);
  ((u16x8*)out)[tid] = h;
}

// features f32 -> f16, 8 elems/thread
__global__ void prepack_feat(const float* __restrict__ F, unsigned short* __restrict__ out,
                             int n8) {
  int i = blockIdx.x * 256 + threadIdx.x;
  if (i >= n8) return;
  const float4* s = (const float4*)(F + (size_t)i * 8);
  float4 v0 = s[0], v1 = s[1];
  float x[8] = {v0.x, v0.y, v0.z, v0.w, v1.x, v1.y, v1.z, v1.w};
  u16x8 o;
#pragma unroll
  for (int e = 0; e < 8; ++e) o[e] = f16bits(x[e]);
  ((u16x8*)out)[i] = o;
}

__global__ void count_labels(const int* __restrict__ labels, int* __restrict__ cnt) {
  int i = blockIdx.x * 256 + threadIdx.x;
  if (i < NPTS) atomicAdd(&cnt[labels[i]], 1);
}

// composed layer-3 gather indices: labels[knn0[.]]
__global__ void compose_idx(const int* __restrict__ knn0, const int* __restrict__ labels,
                            int* __restrict__ out) {
  int i = blockIdx.x * 256 + threadIdx.x;
  if (i < NPTS * 8) out[i] = labels[knn0[i]];
}

__global__ void finalize_pool(const int* __restrict__ pool, const int* __restrict__ cnt,
                              unsigned short* __restrict__ out) {
  int i = blockIdx.x * 256 + threadIdx.x;
  if (i >= N1PTS * 256) return;
  float denom = fmaxf((float)cnt[i >> 8], 1.0f);
  out[i] = f16bits(((float)pool[i]) * (1.0f / 16777216.0f) / denom);
}

// ---------------- Layer 0 ----------------
// 1563 blocks x 512 thr (8 waves, 2x4). Tile 64 rows x 256 cols; wave (wr,wc)
// owns rows [wr*32,+32) x cols [wc*64,+64) -> acc[2][4].
// A: gll staging, 4 LDS buffers, 3 chunks ahead, counted-vmcnt barriers.
// B: coalesced fragment-packed weights (L2-resident 1MB) straight to regs.
__global__ __launch_bounds__(512, 4) void conv0_gemm(
    const unsigned short* __restrict__ F16, const int* __restrict__ idx,
    const int* __restrict__ lab, const unsigned short* __restrict__ Wpk,
    const float* __restrict__ bias, int* __restrict__ pool) {
  __shared__ alignas(16) unsigned short sA[4][64 * 64];  // 8KB x4

  const int t = threadIdx.x;
  const int w = t >> 6, l = t & 63;
  const int lr = l & 15, lh = l >> 4;
  const int wr = w >> 2, wc = w & 3;
  const int row0 = blockIdx.x * 64;

  // staging: wave w stages rows [w*8,+8); lane l -> row w*8+(l>>3), dest seg l&7
  const int strow = w * 8 + (l >> 3);
  const int sseg_src = (l & 7) ^ ((l >> 3) & 7);  // XOR seg swizzle (source side)

  // hoist this staging-row's 8 neighbor ids
  int nbs[8];
  {
    const int grow = row0 + strow;
    const int rr = (grow < NPTS) ? grow : 0;
    const int4* ip = (const int4*)(idx + rr * 8);
    int4 i0 = ip[0], i1 = ip[1];
    nbs[0] = i0.x; nbs[1] = i0.y; nbs[2] = i0.z; nbs[3] = i0.w;
    nbs[4] = i1.x; nbs[5] = i1.y; nbs[6] = i1.z; nbs[7] = i1.w;
  }

  f32x4 acc[2][4] = {};

  auto stage = [&](int cc) {  // cc = chunk mod 32; one gll (1KB/wave)
    const unsigned short* gp =
        F16 + ((size_t)nbs[cc >> 2] << 8) + ((cc & 3) << 6) + sseg_src * 8;
    unsigned short* lp = (unsigned short*)sA + (size_t)(cc & 3) * 4096 + w * 512;
    gload_lds16(gp, lp);
  };

  // prologue: stage chunks 0,1,2; wait chunk 0 only
  stage(0); stage(1); stage(2);
  asm volatile("s_waitcnt vmcnt(2)" ::: "memory");
  __builtin_amdgcn_sched_barrier(0);
  __builtin_amdgcn_s_barrier();
  __builtin_amdgcn_sched_barrier(0);

#pragma unroll 1
  for (int c = 0; c < 32; ++c) {
    // B fragments first (older than this iter's gll -> B waits never drain it)
    f16x8 bh[2][4];
#pragma unroll
    for (int s = 0; s < 2; ++s)
#pragma unroll
      for (int n = 0; n < 4; ++n) {
        const size_t base = ((((size_t)c * 4 + wc) * 4 + n) * 2 + s) * 512 + (size_t)l * 8;
        bh[s][n] = *(const f16x8*)(Wpk + base);
      }

    // prefetch chunk c+3 (wraps harmlessly into dead buffers at tail)
    stage((c + 3) & 31);

    // A frags from LDS + MFMA
    const unsigned short* bufp = (const unsigned short*)sA + (size_t)(c & 3) * 4096;
#pragma unroll
    for (int s = 0; s < 2; ++s) {
      f16x8 a[2];
#pragma unroll
      for (int m = 0; m < 2; ++m) {
        const int seg = ((s << 2) + lh) ^ (lr & 7);
        a[m] = *(const f16x8*)&bufp[(wr * 32 + m * 16 + lr) * 64 + (seg << 3)];
      }
#pragma unroll
      for (int n = 0; n < 4; ++n)
#pragma unroll
        for (int m = 0; m < 2; ++m)
          acc[m][n] = __builtin_amdgcn_mfma_f32_16x16x32_f16(a[m], bh[s][n], acc[m][n], 0, 0, 0);
    }

    // counted-vmcnt barrier: drain gll(c+1)+B(c); keep gll(c+2),gll(c+3)
    __builtin_amdgcn_sched_barrier(0);
    asm volatile("s_waitcnt vmcnt(2)" ::: "memory");
    __builtin_amdgcn_sched_barrier(0);
    __builtin_amdgcn_s_barrier();
    __builtin_amdgcn_sched_barrier(0);
  }
  // drain remaining gll before epilogue/wave-exit (LDS gets reallocated)
  asm volatile("s_waitcnt vmcnt(0)" ::: "memory");

  // epilogue: C frag col = lane&15, row = (lane>>4)*4 + r
  float bv[4];
#pragma unroll
  for (int n = 0; n < 4; ++n) bv[n] = bias[wc * 64 + n * 16 + lr];
#pragma unroll
  for (int m = 0; m < 2; ++m) {
#pragma unroll
    for (int r = 0; r < 4; ++r) {
      const int i = row0 + wr * 32 + m * 16 + lh * 4 + r;
      if (i < NPTS) {
        const int lb = lab[i];
#pragma unroll
        for (int n = 0; n < 4; ++n) {
          float z = acc[m][n][r] + bv[n];
          z = 1.0f / (1.0f + expf(-z));
          atomicAdd(&pool[(size_t)lb * 256 + (wc * 64 + n * 16 + lr)],
                    __float2int_rn(z * 16777216.0f));
        }
      }
    }
  }
}

// ---------------- Layers 1-4: LDS-staged f16 GEMM, f16 activations ----------
template <bool ACT, bool OUT16>
__global__ __launch_bounds__(256, 2) void conv_gemm(
    const unsigned short* __restrict__ act16, const int* __restrict__ idx,
    const unsigned short* __restrict__ Wf, const float* __restrict__ bias,
    void* __restrict__ outp, int M, int cinShift, int Cout, int Ktot) {
  __shared__ alignas(16) unsigned short sAh[4096];
  __shared__ alignas(16) unsigned short sBh[4096];

  const int Cin = 1 << cinShift;
  const int t = threadIdx.x;
  const int bm = blockIdx.x, bn = blockIdx.y;

  const int sr = t >> 2;
  const int kseg = (t & 3) << 4;
  const int ai = bm * 64 + sr;
  const int bco = bn * 64 + sr;

  f32x4 acc[4] = {};

  const int nch = Ktot >> 6;
  for (int kc = 0; kc < nch; ++kc) {
    const int kg = (kc << 6) + kseg;

    u16x8 h0 = {}, h1 = {};
    if (ai < M) {
      const int j = kg >> cinShift;
      const int nbv = idx[ai * 8 + j];
      const unsigned short* src = act16 + ((size_t)nbv << cinShift) + (kg & (Cin - 1));
      h0 = ((const u16x8*)src)[0];
      h1 = ((const u16x8*)src)[1];
    }

    u16x8 bh0 = {}, bh1 = {};
    if (bco < Cout) {
      const unsigned short* sw = Wf + (size_t)bco * Ktot + kg;
      bh0 = ((const u16x8*)sw)[0];
      bh1 = ((const u16x8*)sw)[1];
    }

    __syncthreads();
    const int w0 = swz(sr, kseg), w1 = swz(sr, kseg + 8);
    *(u16x8*)&sAh[w0] = h0; *(u16x8*)&sAh[w1] = h1;
    *(u16x8*)&sBh[w0] = bh0; *(u16x8*)&sBh[w1] = bh1;
    __syncthreads();

    const int l = t & 63;
    const int lr = l & 15, lh = l >> 4;
    const int wid = t >> 6;
#pragma unroll
    for (int s = 0; s < 2; ++s) {
      const int kb = s * 32 + lh * 8;
      const int boff = swz(wid * 16 + lr, kb);
      f16x8 bh = *(const f16x8*)&sBh[boff];
#pragma unroll
      for (int m = 0; m < 4; ++m) {
        const int aoff = swz(m * 16 + lr, kb);
        f16x8 ah = *(const f16x8*)&sAh[aoff];
        acc[m] = __builtin_amdgcn_mfma_f32_16x16x32_f16(ah, bh, acc[m], 0, 0, 0);
      }
    }
  }

  const int l = t & 63, wid = t >> 6;
  const int lr = l & 15, lh = l >> 4;
  const int co = bn * 64 + wid * 16 + lr;
  if (co < Cout) {
    const float bvv = bias[co];
#pragma unroll
    for (int m = 0; m < 4; ++m) {
#pragma unroll
      for (int r = 0; r < 4; ++r) {
        const int i = bm * 64 + m * 16 + lh * 4 + r;
        if (i < M) {
          float z = acc[m][r] + bvv;
          if (ACT) z = 1.0f / (1.0f + expf(-z));
          if (OUT16)
            ((unsigned short*)outp)[(size_t)i * Cout + co] = f16bits(z);
          else
            ((float*)outp)[(size_t)i * Cout + co] = z;
        }
      }
    }
  }
}

extern "C" void kernel_launch(void* const* d_in, const int* in_sizes, int n_in,
                              void* d_out, int out_size, void* d_ws, size_t ws_size,
                              hipStream_t stream) {
  const float* features = (const float*)d_in[0];
  const int* knn0 = (const int*)d_in[1];
  const int* knn1 = (const int*)d_in[2];
  const int* labels = (const int*)d_in[3];
  const float* kw[5] = {(const float*)d_in[4], (const float*)d_in[6],
                        (const float*)d_in[8], (const float*)d_in[10],
                        (const float*)d_in[12]};
  const float* bw[5] = {(const float*)d_in[5], (const float*)d_in[7],
                        (const float*)d_in[9], (const float*)d_in[11],
                        (const float*)d_in[13]};

  char* ws = (char*)d_ws;
  size_t off = 0;
  auto alloc = [&](size_t bytes) -> void* {
    void* p = ws + off;
    off = (off + bytes + 255) & ~(size_t)255;
    return p;
  };
  unsigned short* Wpk0 = (unsigned short*)alloc((size_t)524288 * 2);
  const int wsz14[4] = {262144, 65536, 16384, 768};
  const int woff14[4] = {0, 262144, 327680, 344064};
  unsigned short* W14 = (unsigned short*)alloc((size_t)344832 * 2);
  int* pool = (int*)alloc((size_t)N1PTS * 256 * 4);
  int* cnt = (int*)alloc((size_t)N1PTS * 4);
  unsigned short* pooled = (unsigned short*)alloc((size_t)N1PTS * 256 * 2);
  unsigned short* f1 = (unsigned short*)alloc((size_t)N1PTS * 128 * 2);
  unsigned short* f2 = (unsigned short*)alloc((size_t)N1PTS * 64 * 2);
  int* idx3 = (int*)alloc((size_t)NPTS * 8 * 4);
  unsigned short* F16 = (unsigned short*)alloc((size_t)NPTS * 256 * 2);
  unsigned short* f3 = (unsigned short*)pool;  // alias: pool consumed before layer 3
  if (off > ws_size) return;

  // 1. prepack weights + features (f16); composed layer-3 indices
  prepack_w0<<<256, 256, 0, stream>>>(kw[0], Wpk0);
  for (int i = 0; i < 4; ++i)
    prepack_w<<<(wsz14[i] + 255) / 256, 256, 0, stream>>>(kw[i + 1], W14 + woff14[i], wsz14[i]);
  prepack_feat<<<(NPTS * 256 / 8 + 255) / 256, 256, 0, stream>>>(features, F16, NPTS * 256 / 8);
  compose_idx<<<(NPTS * 8 + 255) / 256, 256, 0, stream>>>(knn0, labels, idx3);

  // 2. zero pool+cnt, histogram labels
  hipMemsetAsync(pool, 0, (size_t)N1PTS * 256 * 4 + (size_t)N1PTS * 4, stream);
  count_labels<<<(NPTS + 255) / 256, 256, 0, stream>>>(labels, cnt);

  // 3. layer 0 + fused fixed-point pool scatter
  conv0_gemm<<<1563, 512, 0, stream>>>(F16, knn0, labels, Wpk0, bw[0], pool);

  // 4. pooled mean -> f16 [N1,256]
  finalize_pool<<<(N1PTS * 256 + 255) / 256, 256, 0, stream>>>(pool, cnt, pooled);

  dim3 blk(256);
  // 5. layer 1: pooled -> f1 [N1,128] f16
  conv_gemm<true, true><<<dim3(196, 2), blk, 0, stream>>>(
      pooled, knn1, W14 + woff14[0], bw[1], f1, N1PTS, 8, 128, 2048);
  // 6. layer 2: f1 -> f2 [N1,64] f16
  conv_gemm<true, true><<<dim3(196, 1), blk, 0, stream>>>(
      f1, knn1, W14 + woff14[1], bw[2], f2, N1PTS, 7, 64, 1024);
  // 7. layer 3: gather f2[idx3] -> f3 [N,32] f16
  conv_gemm<true, true><<<dim3(1563, 1), blk, 0, stream>>>(
      f2, idx3, W14 + woff14[2], bw[3], f3, NPTS, 6, 32, 512);
  // 8. layer 4: f3 -> out [N,3] f32, no activation
  conv_gemm<false, false><<<dim3(1563, 1), blk, 0, stream>>>(
      f3, knn0, W14 + woff14[3], bw[4], (float*)d_out, NPTS, 5, 3, 256);
}

// Round 7
// 302.262 us; speedup vs baseline: 1.2810x; 1.2810x over previous
//
#include <hip/hip_runtime.h>
#include <hip/hip_bf16.h>

// GaussianConv: 5-layer KNN conv net on point cloud.
// R7: conv0 = R4 geometry (4 waves, 64x256, acc[4][4]) + event-ordered
// counted-vmcnt pipeline:
//  - B weights double-buffered in REGISTERS (loaded during prev iter's MFMA)
//  - A gathered via global_load_lds, 4 LDS buffers, issued 2 chunks ahead
//  - A fragments read via inline-asm ds_read_b128 (bypasses compiler's
//    LDS-DMA alias tracking that would insert vmcnt(0))
//  - end-of-iter s_waitcnt vmcnt(12) drains exactly gll(c+1); deeper
//    prefetches stay in flight across the barrier
// Layers 1-4 unchanged (f16 activations, composed idx3).

typedef __attribute__((ext_vector_type(8))) _Float16 f16x8;
typedef __attribute__((ext_vector_type(4))) float f32x4;
typedef __attribute__((ext_vector_type(8))) unsigned short u16x8;

#define NPTS 100000
#define N1PTS 12500

__device__ __forceinline__ void gload_lds16(const unsigned short* g, unsigned short* l) {
  __builtin_amdgcn_global_load_lds(
      (const __attribute__((address_space(1))) void*)g,
      (__attribute__((address_space(3))) void*)l, 16, 0, 0);
}

// Swizzled LDS offset for [64 rows][64 k] f16 tiles (layers 1-4 kernel).
__device__ __forceinline__ int swz(int r, int k) {
  return r * 64 + ((((k >> 3) ^ r) & 7) << 3) + (k & 7);
}

__device__ __forceinline__ unsigned short f16bits(float x) {
  return __builtin_bit_cast(unsigned short, (_Float16)x);
}

// layers 1-4 weights: f32 -> f16 row-major
__global__ void prepack_w(const float* __restrict__ W, unsigned short* __restrict__ out,
                          int n) {
  int i = blockIdx.x * 256 + threadIdx.x;
  if (i < n) out[i] = f16bits(W[i]);
}

// Layer-0 weights -> MFMA-fragment-native packed f16:
// group g = (((c*4 + w)*4 + n)*2 + s), lane l, elem e:
//   dest[g*512 + l*8 + e] = W[w*64+n*16+(l&15)][c*64 + s*32 + (l>>4)*8 + e]
__global__ void prepack_w0(const float* __restrict__ W, unsigned short* __restrict__ out) {
  const int tid = blockIdx.x * 256 + threadIdx.x;  // 65536 total
  const int l = tid & 63;
  const int s = (tid >> 6) & 1;
  const int n = (tid >> 7) & 3;
  const int w = (tid >> 9) & 3;
  const int c = tid >> 11;  // 0..31
  const int co = w * 64 + n * 16 + (l & 15);
  const int k = c * 64 + s * 32 + ((l >> 4) << 3);
  const float* src = W + (size_t)co * 2048 + k;
  u16x8 h;
#pragma unroll
  for (int e = 0; e < 8; ++e) h[e] = f16bits(src[e]);
  ((u16x8*)out)[tid] = h;
}

// features f32 -> f16, 8 elems/thread
__global__ void prepack_feat(const float* __restrict__ F, unsigned short* __restrict__ out,
                             int n8) {
  int i = blockIdx.x * 256 + threadIdx.x;
  if (i >= n8) return;
  const float4* s = (const float4*)(F + (size_t)i * 8);
  float4 v0 = s[0], v1 = s[1];
  float x[8] = {v0.x, v0.y, v0.z, v0.w, v1.x, v1.y, v1.z, v1.w};
  u16x8 o;
#pragma unroll
  for (int e = 0; e < 8; ++e) o[e] = f16bits(x[e]);
  ((u16x8*)out)[i] = o;
}

__global__ void count_labels(const int* __restrict__ labels, int* __restrict__ cnt) {
  int i = blockIdx.x * 256 + threadIdx.x;
  if (i < NPTS) atomicAdd(&cnt[labels[i]], 1);
}

// composed layer-3 gather indices: labels[knn0[.]]
__global__ void compose_idx(const int* __restrict__ knn0, const int* __restrict__ labels,
                            int* __restrict__ out) {
  int i = blockIdx.x * 256 + threadIdx.x;
  if (i < NPTS * 8) out[i] = labels[knn0[i]];
}

__global__ void finalize_pool(const int* __restrict__ pool, const int* __restrict__ cnt,
                              unsigned short* __restrict__ out) {
  int i = blockIdx.x * 256 + threadIdx.x;
  if (i >= N1PTS * 256) return;
  float denom = fmaxf((float)cnt[i >> 8], 1.0f);
  out[i] = f16bits(((float)pool[i]) * (1.0f / 16777216.0f) / denom);
}

// ---------------- Layer 0 ----------------
// 1563 blocks x 256 thr (4 waves). Tile 64 rows x 256 cols; wave w owns cols
// [w*64,+64) -> acc[4][4]. Pipeline per iter c:
//   [asm ds_read A(c) x8; lgkm(0); MFMA x32 (consumes reg-dbuf B(c)) with
//    B(c+1) x8 loads interleaved] ; nb(c+3) x2 ; gll(c+2) x2 ;
//   s_waitcnt vmcnt(12) ; s_barrier
__global__ __launch_bounds__(256, 3) void conv0_gemm(
    const unsigned short* __restrict__ F16, const int* __restrict__ idx,
    const int* __restrict__ lab, const unsigned short* __restrict__ Wpk,
    const float* __restrict__ bias, int* __restrict__ pool) {
  __shared__ alignas(16) unsigned short sA[4][64 * 64];  // 8KB x 4

  const int t = threadIdx.x;
  const int w = t >> 6, l = t & 63;
  const int lr = l & 15, lh = l >> 4;
  const int row0 = blockIdx.x * 64;

  // staging geometry: wave w stages rows [w*16,+16) via 2 gll (8 rows each)
  const int srow8 = l >> 3;                    // row within 8-row group
  const int sseg_src = (l & 7) ^ (srow8 & 7);  // source-side XOR seg swizzle

  // LDS byte base + per-fragment byte offsets (buffer-0-relative)
  const unsigned ldsbase = (unsigned)(uintptr_t)&sA[0][0];
  unsigned aoff[4][2];
#pragma unroll
  for (int m = 0; m < 4; ++m)
#pragma unroll
    for (int s = 0; s < 2; ++s)
      aoff[m][s] =
          ldsbase + (((m * 16 + lr) * 64 + ((((s << 2) + lh) ^ (lr & 7)) << 3)) << 1);

  auto ldnb = [&](int cc, int q) -> int {
    int grow = row0 + w * 16 + q * 8 + srow8;
    grow = grow < NPTS ? grow : NPTS - 1;
    return idx[grow * 8 + ((cc & 31) >> 2)];
  };
  auto stage_q = [&](int cc, int nb, int q) {
    const unsigned short* gp =
        F16 + ((size_t)nb << 8) + ((cc & 3) << 6) + sseg_src * 8;
    unsigned short* lp = &sA[cc & 3][(w * 16 + q * 8) * 64];
    gload_lds16(gp, lp);
  };
  auto loadB = [&](int cc, f16x8 (&bh)[2][4]) {
#pragma unroll
    for (int s = 0; s < 2; ++s)
#pragma unroll
      for (int n = 0; n < 4; ++n)
        bh[s][n] = *(const f16x8*)(
            Wpk + ((((size_t)cc * 4 + w) * 4 + n) * 2 + s) * 512 + (size_t)l * 8);
  };

  f32x4 acc[4][4] = {};
  f16x8 bh[2][4];

  // ---- prologue: nb(0,1,2), B(0), gll(0), gll(1)
  int n00 = ldnb(0, 0), n01 = ldnb(0, 1);
  int n10 = ldnb(1, 0), n11 = ldnb(1, 1);
  int nc0 = ldnb(2, 0), nc1 = ldnb(2, 1);
  loadB(0, bh);
  stage_q(0, n00, 0); stage_q(0, n01, 1);
  stage_q(1, n10, 0); stage_q(1, n11, 1);
  __builtin_amdgcn_sched_barrier(0);
  asm volatile("s_waitcnt vmcnt(2)" ::: "memory");  // drain gll(0); keep gll(1)
  __builtin_amdgcn_sched_barrier(0);
  __builtin_amdgcn_s_barrier();
  __builtin_amdgcn_sched_barrier(0);

#pragma unroll 1
  for (int c = 0; c < 32; ++c) {
    const unsigned bb = (unsigned)((c & 3) << 13);  // LDS buffer byte base

    // A fragments for this chunk: 8x asm ds_read_b128 (compiler can't see
    // these as LDS reads -> no auto vmcnt(0) against the gll queue)
    f16x8 av[4][2];
    asm volatile("ds_read_b128 %0, %1" : "=v"(av[0][0]) : "v"(aoff[0][0] + bb));
    asm volatile("ds_read_b128 %0, %1" : "=v"(av[1][0]) : "v"(aoff[1][0] + bb));
    asm volatile("ds_read_b128 %0, %1" : "=v"(av[2][0]) : "v"(aoff[2][0] + bb));
    asm volatile("ds_read_b128 %0, %1" : "=v"(av[3][0]) : "v"(aoff[3][0] + bb));
    asm volatile("ds_read_b128 %0, %1" : "=v"(av[0][1]) : "v"(aoff[0][1] + bb));
    asm volatile("ds_read_b128 %0, %1" : "=v"(av[1][1]) : "v"(aoff[1][1] + bb));
    asm volatile("ds_read_b128 %0, %1" : "=v"(av[2][1]) : "v"(aoff[2][1] + bb));
    asm volatile("ds_read_b128 %0, %1" : "=v"(av[3][1]) : "v"(aoff[3][1] + bb));
    asm volatile("s_waitcnt lgkmcnt(0)");
    __builtin_amdgcn_sched_barrier(0);

    // MFMA x32 consuming bh (loaded last iter; auto-wait keeps gll queue)
    // + B(c+1) reloads (WAR-ordered after last read of each bh reg)
    f16x8 bnext[2][4];
    loadB((c + 1) & 31, bnext);
#pragma unroll
    for (int s = 0; s < 2; ++s)
#pragma unroll
      for (int n = 0; n < 4; ++n)
#pragma unroll
        for (int m = 0; m < 4; ++m)
          acc[m][n] =
              __builtin_amdgcn_mfma_f32_16x16x32_f16(av[m][s], bh[s][n], acc[m][n], 0, 0, 0);
#pragma unroll
    for (int s = 0; s < 2; ++s)
#pragma unroll
      for (int n = 0; n < 4; ++n)
        bh[s][n] = bnext[s][n];
    __builtin_amdgcn_sched_barrier(0);

    // nb for chunk c+3 (BEFORE gll so waiting nb never drains gll(c+2))
    const int cn = (c + 3) & 31;
    int t0 = ldnb(cn, 0), t1 = ldnb(cn, 1);
    // gll prefetch for chunk c+2
    const int cg = (c + 2) & 31;
    stage_q(cg, nc0, 0); stage_q(cg, nc1, 1);
    __builtin_amdgcn_sched_barrier(0);
    // drain exactly gll(c+1); keep B(c+1) 8 + nb(c+3) 2 + gll(c+2) 2 = 12
    asm volatile("s_waitcnt vmcnt(12)" ::: "memory");
    __builtin_amdgcn_sched_barrier(0);
    __builtin_amdgcn_s_barrier();
    __builtin_amdgcn_sched_barrier(0);
    nc0 = t0; nc1 = t1;
  }
  asm volatile("s_waitcnt vmcnt(0)" ::: "memory");

  // epilogue: C frag col = lane&15, row = (lane>>4)*4 + r
  float bv[4];
#pragma unroll
  for (int n = 0; n < 4; ++n) bv[n] = bias[w * 64 + n * 16 + lr];
#pragma unroll
  for (int m = 0; m < 4; ++m) {
#pragma unroll
    for (int r = 0; r < 4; ++r) {
      const int i = row0 + m * 16 + lh * 4 + r;
      if (i < NPTS) {
        const int lb = lab[i];
#pragma unroll
        for (int n = 0; n < 4; ++n) {
          float z = acc[m][n][r] + bv[n];
          z = 1.0f / (1.0f + expf(-z));
          atomicAdd(&pool[(size_t)lb * 256 + (w * 64 + n * 16 + lr)],
                    __float2int_rn(z * 16777216.0f));
        }
      }
    }
  }
}

// ---------------- Layers 1-4: LDS-staged f16 GEMM, f16 activations ----------
template <bool ACT, bool OUT16>
__global__ __launch_bounds__(256, 2) void conv_gemm(
    const unsigned short* __restrict__ act16, const int* __restrict__ idx,
    const unsigned short* __restrict__ Wf, const float* __restrict__ bias,
    void* __restrict__ outp, int M, int cinShift, int Cout, int Ktot) {
  __shared__ alignas(16) unsigned short sAh[4096];
  __shared__ alignas(16) unsigned short sBh[4096];

  const int Cin = 1 << cinShift;
  const int t = threadIdx.x;
  const int bm = blockIdx.x, bn = blockIdx.y;

  const int sr = t >> 2;
  const int kseg = (t & 3) << 4;
  const int ai = bm * 64 + sr;
  const int bco = bn * 64 + sr;

  f32x4 acc[4] = {};

  const int nch = Ktot >> 6;
  for (int kc = 0; kc < nch; ++kc) {
    const int kg = (kc << 6) + kseg;

    u16x8 h0 = {}, h1 = {};
    if (ai < M) {
      const int j = kg >> cinShift;
      const int nbv = idx[ai * 8 + j];
      const unsigned short* src = act16 + ((size_t)nbv << cinShift) + (kg & (Cin - 1));
      h0 = ((const u16x8*)src)[0];
      h1 = ((const u16x8*)src)[1];
    }

    u16x8 bh0 = {}, bh1 = {};
    if (bco < Cout) {
      const unsigned short* sw = Wf + (size_t)bco * Ktot + kg;
      bh0 = ((const u16x8*)sw)[0];
      bh1 = ((const u16x8*)sw)[1];
    }

    __syncthreads();
    const int w0 = swz(sr, kseg), w1 = swz(sr, kseg + 8);
    *(u16x8*)&sAh[w0] = h0; *(u16x8*)&sAh[w1] = h1;
    *(u16x8*)&sBh[w0] = bh0; *(u16x8*)&sBh[w1] = bh1;
    __syncthreads();

    const int l = t & 63;
    const int lr = l & 15, lh = l >> 4;
    const int wid = t >> 6;
#pragma unroll
    for (int s = 0; s < 2; ++s) {
      const int kb = s * 32 + lh * 8;
      const int boff = swz(wid * 16 + lr, kb);
      f16x8 bh = *(const f16x8*)&sBh[boff];
#pragma unroll
      for (int m = 0; m < 4; ++m) {
        const int aoff = swz(m * 16 + lr, kb);
        f16x8 ah = *(const f16x8*)&sAh[aoff];
        acc[m] = __builtin_amdgcn_mfma_f32_16x16x32_f16(ah, bh, acc[m], 0, 0, 0);
      }
    }
  }

  const int l = t & 63, wid = t >> 6;
  const int lr = l & 15, lh = l >> 4;
  const int co = bn * 64 + wid * 16 + lr;
  if (co < Cout) {
    const float bvv = bias[co];
#pragma unroll
    for (int m = 0; m < 4; ++m) {
#pragma unroll
      for (int r = 0; r < 4; ++r) {
        const int i = bm * 64 + m * 16 + lh * 4 + r;
        if (i < M) {
          float z = acc[m][r] + bvv;
          if (ACT) z = 1.0f / (1.0f + expf(-z));
          if (OUT16)
            ((unsigned short*)outp)[(size_t)i * Cout + co] = f16bits(z);
          else
            ((float*)outp)[(size_t)i * Cout + co] = z;
        }
      }
    }
  }
}

extern "C" void kernel_launch(void* const* d_in, const int* in_sizes, int n_in,
                              void* d_out, int out_size, void* d_ws, size_t ws_size,
                              hipStream_t stream) {
  const float* features = (const float*)d_in[0];
  const int* knn0 = (const int*)d_in[1];
  const int* knn1 = (const int*)d_in[2];
  const int* labels = (const int*)d_in[3];
  const float* kw[5] = {(const float*)d_in[4], (const float*)d_in[6],
                        (const float*)d_in[8], (const float*)d_in[10],
                        (const float*)d_in[12]};
  const float* bw[5] = {(const float*)d_in[5], (const float*)d_in[7],
                        (const float*)d_in[9], (const float*)d_in[11],
                        (const float*)d_in[13]};

  char* ws = (char*)d_ws;
  size_t off = 0;
  auto alloc = [&](size_t bytes) -> void* {
    void* p = ws + off;
    off = (off + bytes + 255) & ~(size_t)255;
    return p;
  };
  unsigned short* Wpk0 = (unsigned short*)alloc((size_t)524288 * 2);
  const int wsz14[4] = {262144, 65536, 16384, 768};
  const int woff14[4] = {0, 262144, 327680, 344064};
  unsigned short* W14 = (unsigned short*)alloc((size_t)344832 * 2);
  int* pool = (int*)alloc((size_t)N1PTS * 256 * 4);
  int* cnt = (int*)alloc((size_t)N1PTS * 4);
  unsigned short* pooled = (unsigned short*)alloc((size_t)N1PTS * 256 * 2);
  unsigned short* f1 = (unsigned short*)alloc((size_t)N1PTS * 128 * 2);
  unsigned short* f2 = (unsigned short*)alloc((size_t)N1PTS * 64 * 2);
  int* idx3 = (int*)alloc((size_t)NPTS * 8 * 4);
  unsigned short* F16 = (unsigned short*)alloc((size_t)NPTS * 256 * 2);
  unsigned short* f3 = (unsigned short*)pool;  // alias: pool consumed before layer 3
  if (off > ws_size) return;

  // 1. prepack weights + features (f16); composed layer-3 indices
  prepack_w0<<<256, 256, 0, stream>>>(kw[0], Wpk0);
  for (int i = 0; i < 4; ++i)
    prepack_w<<<(wsz14[i] + 255) / 256, 256, 0, stream>>>(kw[i + 1], W14 + woff14[i], wsz14[i]);
  prepack_feat<<<(NPTS * 256 / 8 + 255) / 256, 256, 0, stream>>>(features, F16, NPTS * 256 / 8);
  compose_idx<<<(NPTS * 8 + 255) / 256, 256, 0, stream>>>(knn0, labels, idx3);

  // 2. zero pool+cnt, histogram labels
  hipMemsetAsync(pool, 0, (size_t)N1PTS * 256 * 4 + (size_t)N1PTS * 4, stream);
  count_labels<<<(NPTS + 255) / 256, 256, 0, stream>>>(labels, cnt);

  // 3. layer 0 + fused fixed-point pool scatter
  conv0_gemm<<<1563, 256, 0, stream>>>(F16, knn0, labels, Wpk0, bw[0], pool);

  // 4. pooled mean -> f16 [N1,256]
  finalize_pool<<<(N1PTS * 256 + 255) / 256, 256, 0, stream>>>(pool, cnt, pooled);

  dim3 blk(256);
  // 5. layer 1: pooled -> f1 [N1,128] f16
  conv_gemm<true, true><<<dim3(196, 2), blk, 0, stream>>>(
      pooled, knn1, W14 + woff14[0], bw[1], f1, N1PTS, 8, 128, 2048);
  // 6. layer 2: f1 -> f2 [N1,64] f16
  conv_gemm<true, true><<<dim3(196, 1), blk, 0, stream>>>(
      f1, knn1, W14 + woff14[1], bw[2], f2, N1PTS, 7, 64, 1024);
  // 7. layer 3: gather f2[idx3] -> f3 [N,32] f16
  conv_gemm<true, true><<<dim3(1563, 1), blk, 0, stream>>>(
      f2, idx3, W14 + woff14[2], bw[3], f3, NPTS, 6, 32, 512);
  // 8. layer 4: f3 -> out [N,3] f32, no activation
  conv_gemm<false, false><<<dim3(1563, 1), blk, 0, stream>>>(
      f3, knn0, W14 + woff14[3], bw[4], (float*)d_out, NPTS, 5, 3, 256);
}

// Round 9
// 298.706 us; speedup vs baseline: 1.2962x; 1.0119x over previous
//
#include <hip/hip_runtime.h>
#include <hip/hip_bf16.h>

// GaussianConv: 5-layer KNN conv net on point cloud.
// R9: conv0 = R7-exact depth-2 counted-vmcnt pipeline (proven accounting:
// prologue vmcnt(2), end-of-iter vmcnt(12)) + split-lgkm MFMA halves +
// strength-reduced B addressing + sched_barrier-pinned PROLOGUE (R8's bug:
// unpinned prologue let nb loads hoist above glls -> vmcnt kept gll(0) in
// flight -> iter-0 ds_read raced LDS-DMA). Split-K x4 layers 1-2 retained.

typedef __attribute__((ext_vector_type(8))) _Float16 f16x8;
typedef __attribute__((ext_vector_type(4))) float f32x4;
typedef __attribute__((ext_vector_type(8))) unsigned short u16x8;

#define NPTS 100000
#define N1PTS 12500

__device__ __forceinline__ void gload_lds16(const unsigned short* g, unsigned short* l) {
  __builtin_amdgcn_global_load_lds(
      (const __attribute__((address_space(1))) void*)g,
      (__attribute__((address_space(3))) void*)l, 16, 0, 0);
}

// Swizzled LDS offset for [64 rows][64 k] f16 tiles (layers 1-4 kernel).
__device__ __forceinline__ int swz(int r, int k) {
  return r * 64 + ((((k >> 3) ^ r) & 7) << 3) + (k & 7);
}

__device__ __forceinline__ unsigned short f16bits(float x) {
  return __builtin_bit_cast(unsigned short, (_Float16)x);
}

// layers 1-4 weights: f32 -> f16 row-major
__global__ void prepack_w(const float* __restrict__ W, unsigned short* __restrict__ out,
                          int n) {
  int i = blockIdx.x * 256 + threadIdx.x;
  if (i < n) out[i] = f16bits(W[i]);
}

// Layer-0 weights -> MFMA-fragment-native packed f16:
// group g = (((c*4 + w)*4 + n)*2 + s), lane l, elem e:
//   dest[g*512 + l*8 + e] = W[w*64+n*16+(l&15)][c*64 + s*32 + (l>>4)*8 + e]
__global__ void prepack_w0(const float* __restrict__ W, unsigned short* __restrict__ out) {
  const int tid = blockIdx.x * 256 + threadIdx.x;  // 65536 total
  const int l = tid & 63;
  const int s = (tid >> 6) & 1;
  const int n = (tid >> 7) & 3;
  const int w = (tid >> 9) & 3;
  const int c = tid >> 11;  // 0..31
  const int co = w * 64 + n * 16 + (l & 15);
  const int k = c * 64 + s * 32 + ((l >> 4) << 3);
  const float* src = W + (size_t)co * 2048 + k;
  u16x8 h;
#pragma unroll
  for (int e = 0; e < 8; ++e) h[e] = f16bits(src[e]);
  ((u16x8*)out)[tid] = h;
}

// features f32 -> f16, 8 elems/thread
__global__ void prepack_feat(const float* __restrict__ F, unsigned short* __restrict__ out,
                             int n8) {
  int i = blockIdx.x * 256 + threadIdx.x;
  if (i >= n8) return;
  const float4* s = (const float4*)(F + (size_t)i * 8);
  float4 v0 = s[0], v1 = s[1];
  float x[8] = {v0.x, v0.y, v0.z, v0.w, v1.x, v1.y, v1.z, v1.w};
  u16x8 o;
#pragma unroll
  for (int e = 0; e < 8; ++e) o[e] = f16bits(x[e]);
  ((u16x8*)out)[i] = o;
}

__global__ void count_labels(const int* __restrict__ labels, int* __restrict__ cnt) {
  int i = blockIdx.x * 256 + threadIdx.x;
  if (i < NPTS) atomicAdd(&cnt[labels[i]], 1);
}

// composed layer-3 gather indices: labels[knn0[.]]
__global__ void compose_idx(const int* __restrict__ knn0, const int* __restrict__ labels,
                            int* __restrict__ out) {
  int i = blockIdx.x * 256 + threadIdx.x;
  if (i < NPTS * 8) out[i] = labels[knn0[i]];
}

__global__ void finalize_pool(const int* __restrict__ pool, const int* __restrict__ cnt,
                              unsigned short* __restrict__ out) {
  int i = blockIdx.x * 256 + threadIdx.x;
  if (i >= N1PTS * 256) return;
  float denom = fmaxf((float)cnt[i >> 8], 1.0f);
  out[i] = f16bits(((float)pool[i]) * (1.0f / 16777216.0f) / denom);
}

// split-K finalize: int fixed-point (2^22) -> +bias -> sigmoid -> f16
__global__ void finalize_splitk(const int* __restrict__ acc, const float* __restrict__ bias,
                                unsigned short* __restrict__ out, int n, int cmask) {
  int i = blockIdx.x * 256 + threadIdx.x;
  if (i >= n) return;
  float z = ((float)acc[i]) * (1.0f / 4194304.0f) + bias[i & cmask];
  out[i] = f16bits(1.0f / (1.0f + expf(-z)));
}

// ---------------- Layer 0 ----------------
// 1563 blocks x 256 thr (4 waves). Tile 64 rows x 256 cols; wave w owns cols
// [w*64,+64) -> acc[4][4]. Depth-2 pipeline, per iter c (all regions pinned):
//   ds_read A(c) s0-grp x4, s1-grp x4 ; lgkm(4) ; [B(c+1) x8 | MFMA s0 x16] ;
//   lgkm(0) ; MFMA s1 x16 ; nb(c+3) x2 ; gll(c+2) x2 ;
//   vmcnt(12) [drains exactly gll(c+1)] ; s_barrier
__global__ __launch_bounds__(256, 3) void conv0_gemm(
    const unsigned short* __restrict__ F16, const int* __restrict__ idx,
    const int* __restrict__ lab, const unsigned short* __restrict__ Wpk,
    const float* __restrict__ bias, int* __restrict__ pool) {
  __shared__ alignas(16) unsigned short sA[4][64 * 64];  // 8KB x 4

  const int t = threadIdx.x;
  const int w = t >> 6, l = t & 63;
  const int lr = l & 15, lh = l >> 4;
  const int row0 = blockIdx.x * 64;

  // staging geometry: wave w stages rows [w*16,+16) via 2 gll (8 rows each)
  const int srow8 = l >> 3;                    // row within 8-row group
  const int sseg_src = (l & 7) ^ (srow8 & 7);  // source-side XOR seg swizzle

  // LDS byte base + per-fragment byte offsets (buffer-0-relative)
  const unsigned ldsbase = (unsigned)(uintptr_t)&sA[0][0];
  unsigned aoff[4][2];
#pragma unroll
  for (int m = 0; m < 4; ++m)
#pragma unroll
    for (int s = 0; s < 2; ++s)
      aoff[m][s] =
          ldsbase + (((m * 16 + lr) * 64 + ((((s << 2) + lh) ^ (lr & 7)) << 3)) << 1);

  // B pointer in f16x8 units; advances 2048/iter; frag offsets n*128+s*64 (imm)
  const f16x8* wp8 = (const f16x8*)Wpk + (size_t)w * 512 + l;

  auto ldnb = [&](int cc, int q) -> int {
    int grow = row0 + w * 16 + q * 8 + srow8;
    grow = grow < NPTS ? grow : NPTS - 1;
    return idx[grow * 8 + ((cc & 31) >> 2)];
  };
  auto stage_q = [&](int cc, int nb, int q) {
    const unsigned short* gp =
        F16 + ((size_t)nb << 8) + ((cc & 3) << 6) + sseg_src * 8;
    unsigned short* lp = &sA[cc & 3][(w * 16 + q * 8) * 64];
    gload_lds16(gp, lp);
  };

  f32x4 acc[4][4] = {};
  f16x8 bh[2][4];

  // ---- prologue (every region pinned; queue order is the written order)
  int n00 = ldnb(0, 0), n01 = ldnb(0, 1);
  int n10 = ldnb(1, 0), n11 = ldnb(1, 1);
  int nc0 = ldnb(2, 0), nc1 = ldnb(2, 1);
  __builtin_amdgcn_sched_barrier(0);
#pragma unroll
  for (int s = 0; s < 2; ++s)
#pragma unroll
    for (int n = 0; n < 4; ++n) bh[s][n] = wp8[n * 128 + s * 64];
  __builtin_amdgcn_sched_barrier(0);
  stage_q(0, n00, 0); stage_q(0, n01, 1);
  __builtin_amdgcn_sched_barrier(0);
  stage_q(1, n10, 0); stage_q(1, n11, 1);
  __builtin_amdgcn_sched_barrier(0);
  // queue: nb(0..2)x6, B(0)x8, gll(0)x2, gll(1)x2 -> keep gll(1) only
  asm volatile("s_waitcnt vmcnt(2)" ::: "memory");
  __builtin_amdgcn_sched_barrier(0);
  __builtin_amdgcn_s_barrier();
  __builtin_amdgcn_sched_barrier(0);

#pragma unroll 1
  for (int c = 0; c < 32; ++c) {
    const unsigned bb = (unsigned)((c & 3) << 13);  // LDS buffer byte base

    // A fragments: s0 group first, s1 group second (DS completes in order)
    f16x8 av[4][2];
    asm volatile("ds_read_b128 %0, %1" : "=v"(av[0][0]) : "v"(aoff[0][0] + bb));
    asm volatile("ds_read_b128 %0, %1" : "=v"(av[1][0]) : "v"(aoff[1][0] + bb));
    asm volatile("ds_read_b128 %0, %1" : "=v"(av[2][0]) : "v"(aoff[2][0] + bb));
    asm volatile("ds_read_b128 %0, %1" : "=v"(av[3][0]) : "v"(aoff[3][0] + bb));
    asm volatile("ds_read_b128 %0, %1" : "=v"(av[0][1]) : "v"(aoff[0][1] + bb));
    asm volatile("ds_read_b128 %0, %1" : "=v"(av[1][1]) : "v"(aoff[1][1] + bb));
    asm volatile("ds_read_b128 %0, %1" : "=v"(av[2][1]) : "v"(aoff[2][1] + bb));
    asm volatile("ds_read_b128 %0, %1" : "=v"(av[3][1]) : "v"(aoff[3][1] + bb));
    __builtin_amdgcn_sched_barrier(0);
    asm volatile("s_waitcnt lgkmcnt(4)");  // s0 group done; s1 in shadow
    __builtin_amdgcn_sched_barrier(0);

    // B(c+1) loads interleave with MFMA s0
    const f16x8* wpn = wp8 + 2048;
    f16x8 bnext[2][4];
#pragma unroll
    for (int s = 0; s < 2; ++s)
#pragma unroll
      for (int n = 0; n < 4; ++n) bnext[s][n] = wpn[n * 128 + s * 64];
#pragma unroll
    for (int n = 0; n < 4; ++n)
#pragma unroll
      for (int m = 0; m < 4; ++m)
        acc[m][n] =
            __builtin_amdgcn_mfma_f32_16x16x32_f16(av[m][0], bh[0][n], acc[m][n], 0, 0, 0);
    __builtin_amdgcn_sched_barrier(0);
    asm volatile("s_waitcnt lgkmcnt(0)");  // s1 group done
    __builtin_amdgcn_sched_barrier(0);
#pragma unroll
    for (int n = 0; n < 4; ++n)
#pragma unroll
      for (int m = 0; m < 4; ++m)
        acc[m][n] =
            __builtin_amdgcn_mfma_f32_16x16x32_f16(av[m][1], bh[1][n], acc[m][n], 0, 0, 0);
#pragma unroll
    for (int s = 0; s < 2; ++s)
#pragma unroll
      for (int n = 0; n < 4; ++n) bh[s][n] = bnext[s][n];
    __builtin_amdgcn_sched_barrier(0);

    // nb for chunk c+3 (own region, before gll)
    const int cn = (c + 3) & 31;
    int t0 = ldnb(cn, 0), t1 = ldnb(cn, 1);
    __builtin_amdgcn_sched_barrier(0);
    // gll prefetch chunk c+2 (depth 2)
    const int cg = (c + 2) & 31;
    stage_q(cg, nc0, 0); stage_q(cg, nc1, 1);
    __builtin_amdgcn_sched_barrier(0);
    // queue: gll(c+1)x2 + [B(c+1)8 + nb2 + gll(c+2)2 = 12] -> drain gll(c+1)
    asm volatile("s_waitcnt vmcnt(12)" ::: "memory");
    __builtin_amdgcn_sched_barrier(0);
    __builtin_amdgcn_s_barrier();
    __builtin_amdgcn_sched_barrier(0);
    nc0 = t0; nc1 = t1;
    wp8 = wpn;
  }
  asm volatile("s_waitcnt vmcnt(0)" ::: "memory");

  // epilogue: C frag col = lane&15, row = (lane>>4)*4 + r
  float bv[4];
#pragma unroll
  for (int n = 0; n < 4; ++n) bv[n] = bias[w * 64 + n * 16 + lr];
#pragma unroll
  for (int m = 0; m < 4; ++m) {
#pragma unroll
    for (int r = 0; r < 4; ++r) {
      const int i = row0 + m * 16 + lh * 4 + r;
      if (i < NPTS) {
        const int lb = lab[i];
#pragma unroll
        for (int n = 0; n < 4; ++n) {
          float z = acc[m][n][r] + bv[n];
          z = 1.0f / (1.0f + expf(-z));
          atomicAdd(&pool[(size_t)lb * 256 + (w * 64 + n * 16 + lr)],
                    __float2int_rn(z * 16777216.0f));
        }
      }
    }
  }
}

// ---------------- Layers 1-4: LDS-staged f16 GEMM ----------------
// SPLITK: blockIdx.z selects k-slice of length ksl; output = int32 fixed-point
// atomics (scale 2^22, bias deferred to finalize). Else: full K, store f16/f32.
template <bool ACT, bool OUT16, bool SPLITK>
__global__ __launch_bounds__(256, 2) void conv_gemm(
    const unsigned short* __restrict__ act16, const int* __restrict__ idx,
    const unsigned short* __restrict__ Wf, const float* __restrict__ bias,
    void* __restrict__ outp, int M, int cinShift, int Cout, int Ktot, int ksl) {
  __shared__ alignas(16) unsigned short sAh[4096];
  __shared__ alignas(16) unsigned short sBh[4096];

  const int Cin = 1 << cinShift;
  const int t = threadIdx.x;
  const int bm = blockIdx.x, bn = blockIdx.y;
  const int kbase = SPLITK ? blockIdx.z * ksl : 0;

  const int sr = t >> 2;
  const int kseg = (t & 3) << 4;
  const int ai = bm * 64 + sr;
  const int bco = bn * 64 + sr;

  f32x4 acc[4] = {};

  const int nch = ksl >> 6;
  for (int kc = 0; kc < nch; ++kc) {
    const int kg = kbase + (kc << 6) + kseg;

    u16x8 h0 = {}, h1 = {};
    if (ai < M) {
      const int j = kg >> cinShift;
      const int nbv = idx[ai * 8 + j];
      const unsigned short* src = act16 + ((size_t)nbv << cinShift) + (kg & (Cin - 1));
      h0 = ((const u16x8*)src)[0];
      h1 = ((const u16x8*)src)[1];
    }

    u16x8 bh0 = {}, bh1 = {};
    if (bco < Cout) {
      const unsigned short* sw = Wf + (size_t)bco * Ktot + kg;
      bh0 = ((const u16x8*)sw)[0];
      bh1 = ((const u16x8*)sw)[1];
    }

    __syncthreads();
    const int w0 = swz(sr, kseg), w1 = swz(sr, kseg + 8);
    *(u16x8*)&sAh[w0] = h0; *(u16x8*)&sAh[w1] = h1;
    *(u16x8*)&sBh[w0] = bh0; *(u16x8*)&sBh[w1] = bh1;
    __syncthreads();

    const int l = t & 63;
    const int lr = l & 15, lh = l >> 4;
    const int wid = t >> 6;
#pragma unroll
    for (int s = 0; s < 2; ++s) {
      const int kb = s * 32 + lh * 8;
      const int boff = swz(wid * 16 + lr, kb);
      f16x8 bh = *(const f16x8*)&sBh[boff];
#pragma unroll
      for (int m = 0; m < 4; ++m) {
        const int aoff = swz(m * 16 + lr, kb);
        f16x8 ah = *(const f16x8*)&sAh[aoff];
        acc[m] = __builtin_amdgcn_mfma_f32_16x16x32_f16(ah, bh, acc[m], 0, 0, 0);
      }
    }
  }

  const int l = t & 63, wid = t >> 6;
  const int lr = l & 15, lh = l >> 4;
  const int co = bn * 64 + wid * 16 + lr;
  if (co < Cout) {
    const float bvv = SPLITK ? 0.0f : bias[co];
#pragma unroll
    for (int m = 0; m < 4; ++m) {
#pragma unroll
      for (int r = 0; r < 4; ++r) {
        const int i = bm * 64 + m * 16 + lh * 4 + r;
        if (i < M) {
          float z = acc[m][r] + bvv;
          if (SPLITK) {
            atomicAdd(&((int*)outp)[(size_t)i * Cout + co],
                      __float2int_rn(z * 4194304.0f));
          } else {
            if (ACT) z = 1.0f / (1.0f + expf(-z));
            if (OUT16)
              ((unsigned short*)outp)[(size_t)i * Cout + co] = f16bits(z);
            else
              ((float*)outp)[(size_t)i * Cout + co] = z;
          }
        }
      }
    }
  }
}

extern "C" void kernel_launch(void* const* d_in, const int* in_sizes, int n_in,
                              void* d_out, int out_size, void* d_ws, size_t ws_size,
                              hipStream_t stream) {
  const float* features = (const float*)d_in[0];
  const int* knn0 = (const int*)d_in[1];
  const int* knn1 = (const int*)d_in[2];
  const int* labels = (const int*)d_in[3];
  const float* kw[5] = {(const float*)d_in[4], (const float*)d_in[6],
                        (const float*)d_in[8], (const float*)d_in[10],
                        (const float*)d_in[12]};
  const float* bw[5] = {(const float*)d_in[5], (const float*)d_in[7],
                        (const float*)d_in[9], (const float*)d_in[11],
                        (const float*)d_in[13]};

  char* ws = (char*)d_ws;
  size_t off = 0;
  auto alloc = [&](size_t bytes) -> void* {
    void* p = ws + off;
    off = (off + bytes + 255) & ~(size_t)255;
    return p;
  };
  unsigned short* Wpk0 = (unsigned short*)alloc((size_t)(524288 + 16384) * 2);  // +OOB slack
  const int wsz14[4] = {262144, 65536, 16384, 768};
  const int woff14[4] = {0, 262144, 327680, 344064};
  unsigned short* W14 = (unsigned short*)alloc((size_t)344832 * 2);
  int* pool = (int*)alloc((size_t)N1PTS * 256 * 4);
  int* cnt = (int*)alloc((size_t)N1PTS * 4);
  int* f1i = (int*)alloc((size_t)N1PTS * 128 * 4);
  int* f2i = (int*)alloc((size_t)N1PTS * 64 * 4);
  unsigned short* pooled = (unsigned short*)alloc((size_t)N1PTS * 256 * 2);
  unsigned short* f1 = (unsigned short*)alloc((size_t)N1PTS * 128 * 2);
  unsigned short* f2 = (unsigned short*)alloc((size_t)N1PTS * 64 * 2);
  int* idx3 = (int*)alloc((size_t)NPTS * 8 * 4);
  unsigned short* F16 = (unsigned short*)alloc((size_t)NPTS * 256 * 2);
  unsigned short* f3 = (unsigned short*)pool;  // alias: pool consumed before layer 3
  if (off > ws_size) return;

  // 1. prepack weights + features (f16); composed layer-3 indices
  prepack_w0<<<256, 256, 0, stream>>>(kw[0], Wpk0);
  for (int i = 0; i < 4; ++i)
    prepack_w<<<(wsz14[i] + 255) / 256, 256, 0, stream>>>(kw[i + 1], W14 + woff14[i], wsz14[i]);
  prepack_feat<<<(NPTS * 256 / 8 + 255) / 256, 256, 0, stream>>>(features, F16, NPTS * 256 / 8);
  compose_idx<<<(NPTS * 8 + 255) / 256, 256, 0, stream>>>(knn0, labels, idx3);

  // 2. zero pool+cnt+f1i+f2i (contiguous allocator region), histogram labels
  hipMemsetAsync(pool, 0, (size_t)((char*)pooled - (char*)pool), stream);
  count_labels<<<(NPTS + 255) / 256, 256, 0, stream>>>(labels, cnt);

  // 3. layer 0 + fused fixed-point pool scatter
  conv0_gemm<<<1563, 256, 0, stream>>>(F16, knn0, labels, Wpk0, bw[0], pool);

  // 4. pooled mean -> f16 [N1,256]
  finalize_pool<<<(N1PTS * 256 + 255) / 256, 256, 0, stream>>>(pool, cnt, pooled);

  dim3 blk(256);
  // 5. layer 1: split-K x4 (K=2048 -> 4x512), int atomics -> finalize
  conv_gemm<true, true, true><<<dim3(196, 2, 4), blk, 0, stream>>>(
      pooled, knn1, W14 + woff14[0], bw[1], f1i, N1PTS, 8, 128, 2048, 512);
  finalize_splitk<<<(N1PTS * 128 + 255) / 256, 256, 0, stream>>>(
      f1i, bw[1], f1, N1PTS * 128, 127);
  // 6. layer 2: split-K x4 (K=1024 -> 4x256)
  conv_gemm<true, true, true><<<dim3(196, 1, 4), blk, 0, stream>>>(
      f1, knn1, W14 + woff14[1], bw[2], f2i, N1PTS, 7, 64, 1024, 256);
  finalize_splitk<<<(N1PTS * 64 + 255) / 256, 256, 0, stream>>>(
      f2i, bw[2], f2, N1PTS * 64, 63);
  // 7. layer 3: gather f2[idx3] -> f3 [N,32] f16
  conv_gemm<true, true, false><<<dim3(1563, 1), blk, 0, stream>>>(
      f2, idx3, W14 + woff14[2], bw[3], f3, NPTS, 6, 32, 512, 512);
  // 8. layer 4: f3 -> out [N,3] f32, no activation
  conv_gemm<false, false, false><<<dim3(1563, 1), blk, 0, stream>>>(
      f3, knn0, W14 + woff14[3], bw[4], (float*)d_out, NPTS, 5, 3, 256, 256);
}

// Round 10
// 286.843 us; speedup vs baseline: 1.3498x; 1.0414x over previous
//
#include <hip/hip_runtime.h>
#include <hip/hip_bf16.h>

// GaussianConv: 5-layer KNN conv net on point cloud.
// R10: conv0 read-ahead pipeline: av(c+1) ds_reads issued during iter c
// (after MFMA), so each iter's MFMA starts with an already-satisfied lgkm.
// Depth-2 gll staging, reg-dbuf B, all regions sched_barrier-pinned, queue
// accounting: enter iter c with [nb(c+3)x2, gll(c+2)x2] in flight.
// Fused prepack_w14 (1 launch) + fused aux (compose_idx+count_labels).
// Layers 1-4 unchanged (split-K x4 on 1-2, f16 activations).

typedef __attribute__((ext_vector_type(8))) _Float16 f16x8;
typedef __attribute__((ext_vector_type(4))) float f32x4;
typedef __attribute__((ext_vector_type(8))) unsigned short u16x8;

#define NPTS 100000
#define N1PTS 12500

__device__ __forceinline__ void gload_lds16(const unsigned short* g, unsigned short* l) {
  __builtin_amdgcn_global_load_lds(
      (const __attribute__((address_space(1))) void*)g,
      (__attribute__((address_space(3))) void*)l, 16, 0, 0);
}

// Swizzled LDS offset for [64 rows][64 k] f16 tiles (layers 1-4 kernel).
__device__ __forceinline__ int swz(int r, int k) {
  return r * 64 + ((((k >> 3) ^ r) & 7) << 3) + (k & 7);
}

__device__ __forceinline__ unsigned short f16bits(float x) {
  return __builtin_bit_cast(unsigned short, (_Float16)x);
}

// Layer-0 weights -> MFMA-fragment-native packed f16:
// group g = (((c*4 + w)*4 + n)*2 + s), lane l, elem e:
//   dest[g*512 + l*8 + e] = W[w*64+n*16+(l&15)][c*64 + s*32 + (l>>4)*8 + e]
__global__ void prepack_w0(const float* __restrict__ W, unsigned short* __restrict__ out) {
  const int tid = blockIdx.x * 256 + threadIdx.x;  // 65536 total
  const int l = tid & 63;
  const int s = (tid >> 6) & 1;
  const int n = (tid >> 7) & 3;
  const int w = (tid >> 9) & 3;
  const int c = tid >> 11;  // 0..31
  const int co = w * 64 + n * 16 + (l & 15);
  const int k = c * 64 + s * 32 + ((l >> 4) << 3);
  const float* src = W + (size_t)co * 2048 + k;
  u16x8 h;
#pragma unroll
  for (int e = 0; e < 8; ++e) h[e] = f16bits(src[e]);
  ((u16x8*)out)[tid] = h;
}

// layers 1-4 weights fused: 4 segments -> one f16 row-major buffer
__global__ void prepack_w14(const float* __restrict__ k1, const float* __restrict__ k2,
                            const float* __restrict__ k3, const float* __restrict__ k4,
                            unsigned short* __restrict__ out) {
  int i = blockIdx.x * 256 + threadIdx.x;
  if (i >= 344832) return;
  float v;
  if (i < 262144) v = k1[i];
  else if (i < 327680) v = k2[i - 262144];
  else if (i < 344064) v = k3[i - 327680];
  else v = k4[i - 344064];
  out[i] = f16bits(v);
}

// features f32 -> f16, 8 elems/thread
__global__ void prepack_feat(const float* __restrict__ F, unsigned short* __restrict__ out,
                             int n8) {
  int i = blockIdx.x * 256 + threadIdx.x;
  if (i >= n8) return;
  const float4* s = (const float4*)(F + (size_t)i * 8);
  float4 v0 = s[0], v1 = s[1];
  float x[8] = {v0.x, v0.y, v0.z, v0.w, v1.x, v1.y, v1.z, v1.w};
  u16x8 o;
#pragma unroll
  for (int e = 0; e < 8; ++e) o[e] = f16bits(x[e]);
  ((u16x8*)out)[i] = o;
}

// fused aux: idx3[i] = labels[knn0[i]] (i < N*8) + label histogram (i < N)
__global__ void fused_aux(const int* __restrict__ knn0, const int* __restrict__ labels,
                          int* __restrict__ idx3, int* __restrict__ cnt) {
  int i = blockIdx.x * 256 + threadIdx.x;
  if (i < NPTS * 8) idx3[i] = labels[knn0[i]];
  if (i < NPTS) atomicAdd(&cnt[labels[i]], 1);
}

__global__ void finalize_pool(const int* __restrict__ pool, const int* __restrict__ cnt,
                              unsigned short* __restrict__ out) {
  int i = blockIdx.x * 256 + threadIdx.x;
  if (i >= N1PTS * 256) return;
  float denom = fmaxf((float)cnt[i >> 8], 1.0f);
  out[i] = f16bits(((float)pool[i]) * (1.0f / 16777216.0f) / denom);
}

// split-K finalize: int fixed-point (2^22) -> +bias -> sigmoid -> f16
__global__ void finalize_splitk(const int* __restrict__ acc, const float* __restrict__ bias,
                                unsigned short* __restrict__ out, int n, int cmask) {
  int i = blockIdx.x * 256 + threadIdx.x;
  if (i >= n) return;
  float z = ((float)acc[i]) * (1.0f / 4194304.0f) + bias[i & cmask];
  out[i] = f16bits(1.0f / (1.0f + expf(-z)));
}

// ---------------- Layer 0 ----------------
// 1563 blocks x 256 thr (4 waves). Tile 64 rows x 256 cols; wave w owns cols
// [w*64,+64) -> acc[4][4]. Read-ahead pipeline: av(c) was ds_read during
// iter c-1; per iter: lgkm(0); [B(c+1) | MFMA x32]; ds_read av(c+1);
// nb(c+4); gll(c+3); bh<-bnext (auto vmcnt(4)); vmcnt(4); barrier.
__global__ __launch_bounds__(256, 3) void conv0_gemm(
    const unsigned short* __restrict__ F16, const int* __restrict__ idx,
    const int* __restrict__ lab, const unsigned short* __restrict__ Wpk,
    const float* __restrict__ bias, int* __restrict__ pool) {
  __shared__ alignas(16) unsigned short sA[4][64 * 64];  // 8KB x 4

  const int t = threadIdx.x;
  const int w = t >> 6, l = t & 63;
  const int lr = l & 15, lh = l >> 4;
  const int row0 = blockIdx.x * 64;

  // staging geometry: wave w stages rows [w*16,+16) via 2 gll (8 rows each)
  const int srow8 = l >> 3;                    // row within 8-row group
  const int sseg_src = (l & 7) ^ (srow8 & 7);  // source-side XOR seg swizzle

  // LDS byte base + per-fragment byte offsets (buffer-0-relative)
  const unsigned ldsbase = (unsigned)(uintptr_t)&sA[0][0];
  unsigned aoff[4][2];
#pragma unroll
  for (int m = 0; m < 4; ++m)
#pragma unroll
    for (int s = 0; s < 2; ++s)
      aoff[m][s] =
          ldsbase + (((m * 16 + lr) * 64 + ((((s << 2) + lh) ^ (lr & 7)) << 3)) << 1);

  // loop-invariant idx row pointers for the two staged 8-row groups
  int g0 = row0 + w * 16 + srow8;      g0 = g0 < NPTS ? g0 : NPTS - 1;
  int g1 = row0 + w * 16 + 8 + srow8;  g1 = g1 < NPTS ? g1 : NPTS - 1;
  const int* idxp0 = idx + g0 * 8;
  const int* idxp1 = idx + g1 * 8;

  // B pointer in f16x8 units; advances 2048/iter; frag offsets n*128+s*64 (imm)
  const f16x8* wp8 = (const f16x8*)Wpk + (size_t)w * 512 + l;

  auto stage_q = [&](int cc, int nb, int q) {
    const unsigned short* gp =
        F16 + ((size_t)nb << 8) + ((cc & 3) << 6) + sseg_src * 8;
    unsigned short* lp = &sA[cc & 3][(w * 16 + q * 8) * 64];
    gload_lds16(gp, lp);
  };

  f32x4 acc[4][4] = {};
  f16x8 bh[2][4];
  f16x8 av[4][2];

  // ---- prologue (pinned; queue order = written order)
  // chunks 0..3 all use neighbor j=0 -> one nb pair serves gll(0..3)
  int n0 = idxp0[0], n1 = idxp1[0];
  __builtin_amdgcn_sched_barrier(0);
#pragma unroll
  for (int s = 0; s < 2; ++s)
#pragma unroll
    for (int n = 0; n < 4; ++n) bh[s][n] = wp8[n * 128 + s * 64];
  __builtin_amdgcn_sched_barrier(0);
  stage_q(0, n0, 0); stage_q(0, n1, 1);
  stage_q(1, n0, 0); stage_q(1, n1, 1);
  stage_q(2, n0, 0); stage_q(2, n1, 1);
  __builtin_amdgcn_sched_barrier(0);
  int nc0 = n0, nc1 = n1;  // nb(3) == nb(0)
  // queue: nb2, B(0)8, gll(0)2, gll(1)2, gll(2)2 -> keep gll(2) only
  asm volatile("s_waitcnt vmcnt(2)" ::: "memory");
  __builtin_amdgcn_sched_barrier(0);
  __builtin_amdgcn_s_barrier();  // all waves' gll(0),gll(1) now complete
  __builtin_amdgcn_sched_barrier(0);
  // av(0) reads (buffer 0) - safe only after the barrier
  asm volatile("ds_read_b128 %0, %1" : "=v"(av[0][0]) : "v"(aoff[0][0]));
  asm volatile("ds_read_b128 %0, %1" : "=v"(av[1][0]) : "v"(aoff[1][0]));
  asm volatile("ds_read_b128 %0, %1" : "=v"(av[2][0]) : "v"(aoff[2][0]));
  asm volatile("ds_read_b128 %0, %1" : "=v"(av[3][0]) : "v"(aoff[3][0]));
  asm volatile("ds_read_b128 %0, %1" : "=v"(av[0][1]) : "v"(aoff[0][1]));
  asm volatile("ds_read_b128 %0, %1" : "=v"(av[1][1]) : "v"(aoff[1][1]));
  asm volatile("ds_read_b128 %0, %1" : "=v"(av[2][1]) : "v"(aoff[2][1]));
  asm volatile("ds_read_b128 %0, %1" : "=v"(av[3][1]) : "v"(aoff[3][1]));
  __builtin_amdgcn_sched_barrier(0);

#pragma unroll 1
  for (int c = 0; c < 32; ++c) {
    // av(c) ready? reads issued last iter (or prologue) + had barrier to land
    asm volatile("s_waitcnt lgkmcnt(0)");
    __builtin_amdgcn_sched_barrier(0);

    // [B(c+1) loads | MFMA x32] - loads interleave under MFMA issue
    const f16x8* wpn = wp8 + 2048;
    f16x8 bnext[2][4];
#pragma unroll
    for (int s = 0; s < 2; ++s)
#pragma unroll
      for (int n = 0; n < 4; ++n) bnext[s][n] = wpn[n * 128 + s * 64];
#pragma unroll
    for (int n = 0; n < 4; ++n)
#pragma unroll
      for (int m = 0; m < 4; ++m)
        acc[m][n] =
            __builtin_amdgcn_mfma_f32_16x16x32_f16(av[m][0], bh[0][n], acc[m][n], 0, 0, 0);
#pragma unroll
    for (int n = 0; n < 4; ++n)
#pragma unroll
      for (int m = 0; m < 4; ++m)
        acc[m][n] =
            __builtin_amdgcn_mfma_f32_16x16x32_f16(av[m][1], bh[1][n], acc[m][n], 0, 0, 0);
    __builtin_amdgcn_sched_barrier(0);

    // ds_read av(c+1) from buffer (c+1)&3 (complete: gll(c+1) drained @ c-1)
    const unsigned bb2 = (unsigned)(((c + 1) & 3) << 13);
    asm volatile("ds_read_b128 %0, %1" : "=v"(av[0][0]) : "v"(aoff[0][0] + bb2));
    asm volatile("ds_read_b128 %0, %1" : "=v"(av[1][0]) : "v"(aoff[1][0] + bb2));
    asm volatile("ds_read_b128 %0, %1" : "=v"(av[2][0]) : "v"(aoff[2][0] + bb2));
    asm volatile("ds_read_b128 %0, %1" : "=v"(av[3][0]) : "v"(aoff[3][0] + bb2));
    asm volatile("ds_read_b128 %0, %1" : "=v"(av[0][1]) : "v"(aoff[0][1] + bb2));
    asm volatile("ds_read_b128 %0, %1" : "=v"(av[1][1]) : "v"(aoff[1][1] + bb2));
    asm volatile("ds_read_b128 %0, %1" : "=v"(av[2][1]) : "v"(aoff[2][1] + bb2));
    asm volatile("ds_read_b128 %0, %1" : "=v"(av[3][1]) : "v"(aoff[3][1] + bb2));
    __builtin_amdgcn_sched_barrier(0);

    // nb for chunk c+4
    const int jn = ((c + 4) & 31) >> 2;
    int t0 = idxp0[jn], t1 = idxp1[jn];
    __builtin_amdgcn_sched_barrier(0);
    // gll prefetch chunk c+3 (uses nc = nb(c+3), in flight -> auto-wait
    // vmcnt(12) here, drains nothing younger)
    const int cg = (c + 3) & 31;
    stage_q(cg, nc0, 0); stage_q(cg, nc1, 1);
    __builtin_amdgcn_sched_barrier(0);
    // copy: auto-wait for B(c+1) = vmcnt(4) (drains gll(c+2) too)
#pragma unroll
    for (int s = 0; s < 2; ++s)
#pragma unroll
      for (int n = 0; n < 4; ++n) bh[s][n] = bnext[s][n];
    __builtin_amdgcn_sched_barrier(0);
    // enforce invariant: keep exactly [nb(c+4)2, gll(c+3)2]
    asm volatile("s_waitcnt vmcnt(4)" ::: "memory");
    __builtin_amdgcn_sched_barrier(0);
    __builtin_amdgcn_s_barrier();
    __builtin_amdgcn_sched_barrier(0);
    nc0 = t0; nc1 = t1;
    wp8 = wpn;
  }
  // drain all pending vm + trailing (dead) av(32) ds_reads before reg reuse
  asm volatile("s_waitcnt vmcnt(0) lgkmcnt(0)" ::: "memory");

  // epilogue: C frag col = lane&15, row = (lane>>4)*4 + r
  float bv[4];
#pragma unroll
  for (int n = 0; n < 4; ++n) bv[n] = bias[w * 64 + n * 16 + lr];
#pragma unroll
  for (int m = 0; m < 4; ++m) {
#pragma unroll
    for (int r = 0; r < 4; ++r) {
      const int i = row0 + m * 16 + lh * 4 + r;
      if (i < NPTS) {
        const int lb = lab[i];
#pragma unroll
        for (int n = 0; n < 4; ++n) {
          float z = acc[m][n][r] + bv[n];
          z = 1.0f / (1.0f + expf(-z));
          atomicAdd(&pool[(size_t)lb * 256 + (w * 64 + n * 16 + lr)],
                    __float2int_rn(z * 16777216.0f));
        }
      }
    }
  }
}

// ---------------- Layers 1-4: LDS-staged f16 GEMM ----------------
// SPLITK: blockIdx.z selects k-slice of length ksl; output = int32 fixed-point
// atomics (scale 2^22, bias deferred to finalize). Else: full K, store f16/f32.
template <bool ACT, bool OUT16, bool SPLITK>
__global__ __launch_bounds__(256, 2) void conv_gemm(
    const unsigned short* __restrict__ act16, const int* __restrict__ idx,
    const unsigned short* __restrict__ Wf, const float* __restrict__ bias,
    void* __restrict__ outp, int M, int cinShift, int Cout, int Ktot, int ksl) {
  __shared__ alignas(16) unsigned short sAh[4096];
  __shared__ alignas(16) unsigned short sBh[4096];

  const int Cin = 1 << cinShift;
  const int t = threadIdx.x;
  const int bm = blockIdx.x, bn = blockIdx.y;
  const int kbase = SPLITK ? blockIdx.z * ksl : 0;

  const int sr = t >> 2;
  const int kseg = (t & 3) << 4;
  const int ai = bm * 64 + sr;
  const int bco = bn * 64 + sr;

  f32x4 acc[4] = {};

  const int nch = ksl >> 6;
  for (int kc = 0; kc < nch; ++kc) {
    const int kg = kbase + (kc << 6) + kseg;

    u16x8 h0 = {}, h1 = {};
    if (ai < M) {
      const int j = kg >> cinShift;
      const int nbv = idx[ai * 8 + j];
      const unsigned short* src = act16 + ((size_t)nbv << cinShift) + (kg & (Cin - 1));
      h0 = ((const u16x8*)src)[0];
      h1 = ((const u16x8*)src)[1];
    }

    u16x8 bh0 = {}, bh1 = {};
    if (bco < Cout) {
      const unsigned short* sw = Wf + (size_t)bco * Ktot + kg;
      bh0 = ((const u16x8*)sw)[0];
      bh1 = ((const u16x8*)sw)[1];
    }

    __syncthreads();
    const int w0 = swz(sr, kseg), w1 = swz(sr, kseg + 8);
    *(u16x8*)&sAh[w0] = h0; *(u16x8*)&sAh[w1] = h1;
    *(u16x8*)&sBh[w0] = bh0; *(u16x8*)&sBh[w1] = bh1;
    __syncthreads();

    const int l = t & 63;
    const int lr = l & 15, lh = l >> 4;
    const int wid = t >> 6;
#pragma unroll
    for (int s = 0; s < 2; ++s) {
      const int kb = s * 32 + lh * 8;
      const int boff = swz(wid * 16 + lr, kb);
      f16x8 bh = *(const f16x8*)&sBh[boff];
#pragma unroll
      for (int m = 0; m < 4; ++m) {
        const int aoff = swz(m * 16 + lr, kb);
        f16x8 ah = *(const f16x8*)&sAh[aoff];
        acc[m] = __builtin_amdgcn_mfma_f32_16x16x32_f16(ah, bh, acc[m], 0, 0, 0);
      }
    }
  }

  const int l = t & 63, wid = t >> 6;
  const int lr = l & 15, lh = l >> 4;
  const int co = bn * 64 + wid * 16 + lr;
  if (co < Cout) {
    const float bvv = SPLITK ? 0.0f : bias[co];
#pragma unroll
    for (int m = 0; m < 4; ++m) {
#pragma unroll
      for (int r = 0; r < 4; ++r) {
        const int i = bm * 64 + m * 16 + lh * 4 + r;
        if (i < M) {
          float z = acc[m][r] + bvv;
          if (SPLITK) {
            atomicAdd(&((int*)outp)[(size_t)i * Cout + co],
                      __float2int_rn(z * 4194304.0f));
          } else {
            if (ACT) z = 1.0f / (1.0f + expf(-z));
            if (OUT16)
              ((unsigned short*)outp)[(size_t)i * Cout + co] = f16bits(z);
            else
              ((float*)outp)[(size_t)i * Cout + co] = z;
          }
        }
      }
    }
  }
}

extern "C" void kernel_launch(void* const* d_in, const int* in_sizes, int n_in,
                              void* d_out, int out_size, void* d_ws, size_t ws_size,
                              hipStream_t stream) {
  const float* features = (const float*)d_in[0];
  const int* knn0 = (const int*)d_in[1];
  const int* knn1 = (const int*)d_in[2];
  const int* labels = (const int*)d_in[3];
  const float* kw[5] = {(const float*)d_in[4], (const float*)d_in[6],
                        (const float*)d_in[8], (const float*)d_in[10],
                        (const float*)d_in[12]};
  const float* bw[5] = {(const float*)d_in[5], (const float*)d_in[7],
                        (const float*)d_in[9], (const float*)d_in[11],
                        (const float*)d_in[13]};

  char* ws = (char*)d_ws;
  size_t off = 0;
  auto alloc = [&](size_t bytes) -> void* {
    void* p = ws + off;
    off = (off + bytes + 255) & ~(size_t)255;
    return p;
  };
  unsigned short* Wpk0 = (unsigned short*)alloc((size_t)(524288 + 16384) * 2);
  const int woff14[4] = {0, 262144, 327680, 344064};
  unsigned short* W14 = (unsigned short*)alloc((size_t)344832 * 2);
  int* pool = (int*)alloc((size_t)N1PTS * 256 * 4);
  int* cnt = (int*)alloc((size_t)N1PTS * 4);
  int* f1i = (int*)alloc((size_t)N1PTS * 128 * 4);
  int* f2i = (int*)alloc((size_t)N1PTS * 64 * 4);
  unsigned short* pooled = (unsigned short*)alloc((size_t)N1PTS * 256 * 2);
  unsigned short* f1 = (unsigned short*)alloc((size_t)N1PTS * 128 * 2);
  unsigned short* f2 = (unsigned short*)alloc((size_t)N1PTS * 64 * 2);
  int* idx3 = (int*)alloc((size_t)NPTS * 8 * 4);
  unsigned short* F16 = (unsigned short*)alloc((size_t)NPTS * 256 * 2);
  unsigned short* f3 = (unsigned short*)pool;  // alias: pool consumed before layer 3
  if (off > ws_size) return;

  // 1. prepack weights + features (f16)
  prepack_w0<<<256, 256, 0, stream>>>(kw[0], Wpk0);
  prepack_w14<<<1347, 256, 0, stream>>>(kw[1], kw[2], kw[3], kw[4], W14);
  prepack_feat<<<(NPTS * 256 / 8 + 255) / 256, 256, 0, stream>>>(features, F16, NPTS * 256 / 8);

  // 2. zero pool+cnt+f1i+f2i (contiguous region), then fused aux
  hipMemsetAsync(pool, 0, (size_t)((char*)pooled - (char*)pool), stream);
  fused_aux<<<(NPTS * 8 + 255) / 256, 256, 0, stream>>>(knn0, labels, idx3, cnt);

  // 3. layer 0 + fused fixed-point pool scatter
  conv0_gemm<<<1563, 256, 0, stream>>>(F16, knn0, labels, Wpk0, bw[0], pool);

  // 4. pooled mean -> f16 [N1,256]
  finalize_pool<<<(N1PTS * 256 + 255) / 256, 256, 0, stream>>>(pool, cnt, pooled);

  dim3 blk(256);
  // 5. layer 1: split-K x4 (K=2048 -> 4x512), int atomics -> finalize
  conv_gemm<true, true, true><<<dim3(196, 2, 4), blk, 0, stream>>>(
      pooled, knn1, W14 + woff14[0], bw[1], f1i, N1PTS, 8, 128, 2048, 512);
  finalize_splitk<<<(N1PTS * 128 + 255) / 256, 256, 0, stream>>>(
      f1i, bw[1], f1, N1PTS * 128, 127);
  // 6. layer 2: split-K x4 (K=1024 -> 4x256)
  conv_gemm<true, true, true><<<dim3(196, 1, 4), blk, 0, stream>>>(
      f1, knn1, W14 + woff14[1], bw[2], f2i, N1PTS, 7, 64, 1024, 256);
  finalize_splitk<<<(N1PTS * 64 + 255) / 256, 256, 0, stream>>>(
      f2i, bw[2], f2, N1PTS * 64, 63);
  // 7. layer 3: gather f2[idx3] -> f3 [N,32] f16
  conv_gemm<true, true, false><<<dim3(1563, 1), blk, 0, stream>>>(
      f2, idx3, W14 + woff14[2], bw[3], f3, NPTS, 6, 32, 512, 512);
  // 8. layer 4: f3 -> out [N,3] f32, no activation
  conv_gemm<false, false, false><<<dim3(1563, 1), blk, 0, stream>>>(
      f3, knn0, W14 + woff14[3], bw[4], (float*)d_out, NPTS, 5, 3, 256, 256);
}